// Round 1
// baseline (120.191 us; speedup 1.0000x reference)
//
#include <hip/hip_runtime.h>

#define BB 128
#define HIDN 1024
#define G3 3072
#define NVOCAB 32000

typedef __bf16 bf16x8 __attribute__((ext_vector_type(8)));
typedef float f32x4 __attribute__((ext_vector_type(4)));

__device__ __forceinline__ unsigned short f2bf(float f) {
  union { float f; unsigned int u; } v; v.f = f;
  unsigned int u = v.u;
  return (unsigned short)((u + 0x7fffu + ((u >> 16) & 1u)) >> 16);
}

__device__ __forceinline__ float sigmoidf_(float x) {
  return 1.0f / (1.0f + __expf(-x));
}

// ---------------------------------------------------------------------------
// Generic 128-row GEMM core: C[0:128][n0:n0+BN] = A(bf16,128xK) @ W(f32,KxN) + bias
// Block = 256 threads (4 waves). BM=128 fixed. BK=32. W converted f32->bf16 on
// the fly into transposed LDS [col][k] (stride 40 ushorts = 80B, 16B-aligned
// per col so ds_read_b128 works), double-buffered.
// ---------------------------------------------------------------------------
template <int BN>
__device__ __forceinline__ void gemm_core(
    const unsigned short* __restrict__ A, int K,
    const float* __restrict__ W, int ldw, int n0,
    const float* __restrict__ bias,
    float* __restrict__ C, int ldc,
    unsigned short* lds) {
  constexpr int BK = 32;
  constexpr int SK = 40;            // lds stride per col (ushorts)
  constexpr int NT = BN / 16;       // col tiles per block
  const int t = threadIdx.x;
  const int lane = t & 63;
  const int wv = t >> 6;            // wave id 0..3 -> row tiles {2wv, 2wv+1}
  const int l15 = lane & 15;
  const int koff = (lane >> 4) * 8; // k offset of this lane's fragment

  f32x4 acc[2][NT];
#pragma unroll
  for (int rt = 0; rt < 2; ++rt)
#pragma unroll
    for (int ct = 0; ct < NT; ++ct)
      acc[rt][ct] = (f32x4)0.0f;

  // stage one BKxBN fp32 tile of W into LDS as bf16, transposed [col][k]
  auto stage_one = [&](unsigned short* buf, int k0, int p, int c4) {
    const float* g = W + (size_t)(k0 + 2 * p) * ldw + n0 + c4;
    float4 ra = *(const float4*)g;
    float4 rb = *(const float4*)(g + ldw);
    const float* pa = (const float*)&ra;
    const float* pb = (const float*)&rb;
#pragma unroll
    for (int i = 0; i < 4; ++i) {
      unsigned int pk = (unsigned int)f2bf(pa[i]) |
                        ((unsigned int)f2bf(pb[i]) << 16);
      *(unsigned int*)&buf[(c4 + i) * SK + 2 * p] = pk;  // [col][k..k+1]
    }
  };
  auto stage = [&](unsigned short* buf, int k0) {
    if (BN == 128) {
#pragma unroll
      for (int j = 0; j < 2; ++j)
        stage_one(buf, k0, (t >> 5) + j * 8, (t & 31) * 4);
    } else {  // BN == 32
      if (t < 128) stage_one(buf, k0, t >> 3, (t & 7) * 4);
    }
  };

  stage(lds, 0);
  __syncthreads();

  const int nk = K / BK;
  for (int kk = 0; kk < nk; ++kk) {
    unsigned short* cur = lds + (kk & 1) * (BN * SK);
    unsigned short* nxt = lds + ((kk + 1) & 1) * (BN * SK);
    if (kk + 1 < nk) stage(nxt, (kk + 1) * BK);

    bf16x8 a[2];
#pragma unroll
    for (int rt = 0; rt < 2; ++rt) {
      int row = (wv * 2 + rt) * 16 + l15;
      a[rt] = *(const bf16x8*)(A + (size_t)row * K + kk * BK + koff);
    }
#pragma unroll
    for (int ct = 0; ct < NT; ++ct) {
      bf16x8 b = *(const bf16x8*)(cur + (ct * 16 + l15) * SK + koff);
#pragma unroll
      for (int rt = 0; rt < 2; ++rt)
        acc[rt][ct] = __builtin_amdgcn_mfma_f32_16x16x32_bf16(
            a[rt], b, acc[rt][ct], 0, 0, 0);
    }
    __syncthreads();
  }

  // epilogue: D lane mapping col = lane&15, row = (lane>>4)*4 + j
#pragma unroll
  for (int rt = 0; rt < 2; ++rt) {
    int rbase = (wv * 2 + rt) * 16 + (lane >> 4) * 4;
#pragma unroll
    for (int ct = 0; ct < NT; ++ct) {
      int col = n0 + ct * 16 + l15;
      float bs = bias ? bias[col] : 0.0f;
#pragma unroll
      for (int j = 0; j < 4; ++j)
        C[(size_t)(rbase + j) * ldc + col] = acc[rt][ct][j] + bs;
    }
  }
}

// ---------------------------------------------------------------------------
// prep: h0,h1 -> bf16 ; embedding gather -> bf16
// ---------------------------------------------------------------------------
__global__ __launch_bounds__(256) void prep_kernel(
    const float* __restrict__ h0, const float* __restrict__ h1,
    const float* __restrict__ emb, const int* __restrict__ x,
    unsigned short* __restrict__ h0b, unsigned short* __restrict__ h1b,
    unsigned short* __restrict__ eb) {
  int i = blockIdx.x * 256 + threadIdx.x;
  if (i < 131072) {
    h0b[i] = f2bf(h0[i]);
  } else if (i < 262144) {
    int j = i - 131072;
    h1b[j] = f2bf(h1[j]);
  } else if (i < 294912) {
    int j = i - 262144;
    int b = j >> 8, c = j & 255;
    eb[j] = f2bf(emb[(size_t)x[b] * 256 + c]);
  }
}

// ---------------------------------------------------------------------------
// GRU gemms: blocks 0..95 -> gi = X@Wi + bi ; blocks 96..191 -> gr = H@Wr + br
// ---------------------------------------------------------------------------
__global__ __launch_bounds__(256) void gru_gemms_kernel(
    const unsigned short* __restrict__ Xbf, int KX,
    const float* __restrict__ Wi, const float* __restrict__ bi,
    const unsigned short* __restrict__ Hbf,
    const float* __restrict__ Wr, const float* __restrict__ br,
    float* __restrict__ gi, float* __restrict__ gr) {
  __shared__ unsigned short lds[2 * 32 * 40];
  int blk = blockIdx.x;
  if (blk < 96)
    gemm_core<32>(Xbf, KX, Wi, G3, blk * 32, bi, gi, G3, lds);
  else
    gemm_core<32>(Hbf, HIDN, Wr, G3, (blk - 96) * 32, br, gr, G3, lds);
}

// ---------------------------------------------------------------------------
// gates: GRU elementwise epilogue; writes h' fp32 (d_out) and bf16 (ws)
// ---------------------------------------------------------------------------
__global__ __launch_bounds__(256) void gates_kernel(
    const float* __restrict__ gi, const float* __restrict__ gr,
    const float* __restrict__ hfp, float* __restrict__ hout,
    unsigned short* __restrict__ hbf) {
  int i = blockIdx.x * 256 + threadIdx.x;  // 131072 total
  int b = i >> 10, n = i & 1023;
  const float* gib = gi + (size_t)b * G3;
  const float* grb = gr + (size_t)b * G3;
  float z = sigmoidf_(gib[n] + grb[n]);
  float r = sigmoidf_(gib[1024 + n] + grb[1024 + n]);
  float hh = tanhf(gib[2048 + n] + r * grb[2048 + n]);
  float h = hfp[i];
  float o = z * h + (1.0f - z) * hh;
  hout[i] = o;
  hbf[i] = f2bf(o);
}

// ---------------------------------------------------------------------------
// FF: logits = h1n @ ffW + ffb   (128x1024 @ 1024x32000)
// ---------------------------------------------------------------------------
__global__ __launch_bounds__(256) void ff_kernel(
    const unsigned short* __restrict__ Abf, const float* __restrict__ W,
    const float* __restrict__ bias, float* __restrict__ C) {
  __shared__ unsigned short lds[2 * 128 * 40];
  gemm_core<128>(Abf, HIDN, W, NVOCAB, blockIdx.x * 128, bias, C, NVOCAB, lds);
}

extern "C" void kernel_launch(void* const* d_in, const int* in_sizes, int n_in,
                              void* d_out, int out_size, void* d_ws,
                              size_t ws_size, hipStream_t stream) {
  const int* x = (const int*)d_in[0];
  const float* h0 = (const float*)d_in[1];
  const float* h1 = (const float*)d_in[2];
  const float* emb = (const float*)d_in[3];
  const float* Wi0 = (const float*)d_in[4];
  const float* Wr0 = (const float*)d_in[5];
  const float* bi0 = (const float*)d_in[6];
  const float* br0 = (const float*)d_in[7];
  const float* Wi1 = (const float*)d_in[8];
  const float* Wr1 = (const float*)d_in[9];
  const float* bi1 = (const float*)d_in[10];
  const float* br1 = (const float*)d_in[11];
  const float* ffW = (const float*)d_in[12];
  const float* ffb = (const float*)d_in[13];

  float* out = (float*)d_out;
  float* logits = out;                       // 128*32000
  float* h0n = out + 4096000;                // 128*1024
  float* h1n = out + 4227072;                // 128*1024

  unsigned short* h0b = (unsigned short*)d_ws;   // 128*1024
  unsigned short* h1b = h0b + 131072;            // 128*1024
  unsigned short* eb = h1b + 131072;             // 128*256
  unsigned short* h0nb = eb + 32768;             // 128*1024
  unsigned short* h1nb = h0nb + 131072;          // 128*1024
  float* gi = (float*)(h1nb + 131072);           // 128*3072
  float* gr = gi + 128 * G3;                     // 128*3072

  prep_kernel<<<1152, 256, 0, stream>>>(h0, h1, emb, x, h0b, h1b, eb);

  // GRU layer 0: x-part uses embedded input (K=256)
  gru_gemms_kernel<<<192, 256, 0, stream>>>(eb, 256, Wi0, bi0, h0b, Wr0, br0,
                                            gi, gr);
  gates_kernel<<<512, 256, 0, stream>>>(gi, gr, h0, h0n, h0nb);

  // GRU layer 1: x-part uses h0n (K=1024)
  gru_gemms_kernel<<<192, 256, 0, stream>>>(h0nb, 1024, Wi1, bi1, h1b, Wr1,
                                            br1, gi, gr);
  gates_kernel<<<512, 256, 0, stream>>>(gi, gr, h1, h1n, h1nb);

  // FF
  ff_kernel<<<250, 256, 0, stream>>>(h1nb, ffW, ffb, logits);
}